// Round 11
// baseline (481.334 us; speedup 1.0000x reference)
//
#include <hip/hip_runtime.h>
#include <hip/hip_bf16.h>

typedef short short4v __attribute__((ext_vector_type(4)));
typedef short short8 __attribute__((ext_vector_type(8)));
typedef float float4v __attribute__((ext_vector_type(4)));

#define HEADS 16
#define HDIM 64
#define TOKDIM 1024
#define SEQ 2048
#define BATCH 2
#define BH (BATCH*HEADS)
#define MROWS (BATCH*SEQ)

__device__ __forceinline__ short f2b(float f) {
    __hip_bfloat16 h = __float2bfloat16(f);
    return *reinterpret_cast<short*>(&h);
}
__device__ __forceinline__ float b2f(short s) {
    __hip_bfloat16 h;
    *reinterpret_cast<short*>(&h) = s;
    return __bfloat162float(h);
}
__device__ __forceinline__ short8 load8_f32_bf16(const float* __restrict__ p) {
    float4v a = *(const float4v*)p;
    float4v b = *(const float4v*)(p + 4);
    short8 r;
    r[0]=f2b(a[0]); r[1]=f2b(a[1]); r[2]=f2b(a[2]); r[3]=f2b(a[3]);
    r[4]=f2b(b[0]); r[5]=f2b(b[1]); r[6]=f2b(b[2]); r[7]=f2b(b[3]);
    return r;
}
// fast pack: RN each fp32 to bf16 (bits+0x8000), byte-pack highs via v_perm
__device__ __forceinline__ int packrn(float a, float b) {
    unsigned ua = __float_as_uint(a) + 0x8000u;
    unsigned ub = __float_as_uint(b) + 0x8000u;
    return (int)__builtin_amdgcn_perm(ub, ua, 0x07060302u);
}
// hardware exp2 (avoid glibc __exp2f macro collision)
__device__ __forceinline__ float hexp2(float x) {
    return __builtin_amdgcn_exp2f(x);
}

// async global->LDS DMA, 16B/lane; LDS dest = wave-uniform base + lane*16
__device__ __forceinline__ void stage16(const void* g, void* l) {
    __builtin_amdgcn_global_load_lds((const __attribute__((address_space(1))) void*)g,
                                     (__attribute__((address_space(3))) void*)l, 16, 0, 0);
}

// ---------------------------------------------------------------------------
// One-time fp32 -> bf16 conversion for x, wqkv, wout.
// ---------------------------------------------------------------------------
__global__ __launch_bounds__(256)
void cvt_bf16(const float* __restrict__ x,  short* __restrict__ xb,  int n8x,
              const float* __restrict__ wq, short* __restrict__ wqb, int n8q,
              const float* __restrict__ wo, short* __restrict__ wob, int n8o)
{
    int i = blockIdx.x*256 + threadIdx.x;
    const float* s; short* d; int off;
    if (i < n8x)                  { s = x;  d = xb;  off = i; }
    else if (i < n8x + n8q)       { s = wq; d = wqb; off = i - n8x; }
    else if (i < n8x + n8q + n8o) { s = wo; d = wob; off = i - n8x - n8q; }
    else return;
    *(short8*)&d[(size_t)off*8] = load8_f32_bf16(&s[(size_t)off*8]);
}

// ---------------------------------------------------------------------------
// QKV GEMM, m97-style staging (unchanged).
// ---------------------------------------------------------------------------
__global__ __launch_bounds__(256)
void gemm_qkv(const short* __restrict__ A, const short* __restrict__ Wq,
              short* __restrict__ Qo, short* __restrict__ Ko, short* __restrict__ Vto)
{
    __shared__ __align__(16) short As[128*32];
    __shared__ __align__(16) short Bs[128*32];
    const int tid  = threadIdx.x;
    const int lane = tid & 63;
    const int wave = tid >> 6;
    const int wm = wave >> 1, wn = wave & 1;
    const int m0 = blockIdx.x * 128;
    const int n0 = blockIdx.y * 128;
    const int col16 = lane & 15, quad = lane >> 4;

    const int srow = lane >> 2;
    const int scol = (lane & 3) * 8;

    float4v acc[4][4];
    #pragma unroll
    for (int i=0;i<4;i++)
        #pragma unroll
        for (int j=0;j<4;j++) acc[i][j] = (float4v){0.f,0.f,0.f,0.f};

    for (int k0 = 0; k0 < TOKDIM; k0 += 32) {
        __syncthreads();
        #pragma unroll
        for (int j=0;j<2;++j) {
            const int rb = (wave*2 + j) * 16;
            stage16(&A[(size_t)(m0 + rb + srow)*TOKDIM + k0 + scol], &As[rb*32]);
        }
        #pragma unroll
        for (int j=0;j<2;++j) {
            const int rb = (wave*2 + j) * 16;
            stage16(&Wq[(size_t)(n0 + rb + srow)*TOKDIM + k0 + scol], &Bs[rb*32]);
        }
        __syncthreads();

        short8 af[4], bfr[4];
        #pragma unroll
        for (int i=0;i<4;i++) af[i]  = *(const short8*)&As[(wm*64 + i*16 + col16)*32 + quad*8];
        #pragma unroll
        for (int j=0;j<4;j++) bfr[j] = *(const short8*)&Bs[(wn*64 + j*16 + col16)*32 + quad*8];
        #pragma unroll
        for (int i=0;i<4;i++)
            #pragma unroll
            for (int j=0;j<4;j++)
                acc[i][j] = __builtin_amdgcn_mfma_f32_16x16x32_bf16(af[i], bfr[j], acc[i][j], 0,0,0);
    }

    #pragma unroll
    for (int i=0;i<4;i++)
        #pragma unroll
        for (int j=0;j<4;j++) {
            const int n = n0 + wn*64 + j*16 + col16;
            const int part = n >> 10;         // 0=Q 1=K 2=V
            const int h = (n & 1023) >> 6;
            const int d = n & 63;
            const int mb = m0 + wm*64 + i*16 + quad*4;
            const int b = mb >> 11;
            const int t = mb & 2047;
            if (part == 2) {
                union { short4v s; int2 i2; } w;
                #pragma unroll
                for (int r=0;r<4;r++) w.s[r] = f2b(acc[i][j][r]);
                *(int2*)&Vto[((size_t)(b*HEADS + h)*HDIM + d)*SEQ + t] = w.i2;
            } else {
                short* dst = (part == 0) ? Qo : Ko;
                #pragma unroll
                for (int r=0;r<4;r++)
                    dst[((size_t)(b*HEADS + h)*SEQ + t + r)*HDIM + d] = f2b(acc[i][j][r]);
            }
        }
}

// ---------------------------------------------------------------------------
// Out GEMM with fused split-K attention merge in the A-staging:
// A[m][k] = (PO0[m][k] + PO1[m][k]) / (PL0[bh][t] + PL1[bh][t]) -> bf16.
// W (bf16) stays DMA-staged. fp32 output + bias.
// ---------------------------------------------------------------------------
__global__ __launch_bounds__(256)
void gemm_out(const float* __restrict__ PO, const float* __restrict__ PL,
              const short* __restrict__ W,
              const float* __restrict__ bias, float* __restrict__ C)
{
    __shared__ __align__(16) short As[64*32];
    __shared__ __align__(16) short Bs[128*32];
    const int tid  = threadIdx.x;
    const int lane = tid & 63;
    const int wave = tid >> 6;
    const int wm = wave >> 1, wn = wave & 1;
    const int m0 = blockIdx.x * 64;
    const int n0 = blockIdx.y * 128;
    const int col16 = lane & 15, quad = lane >> 4;

    const int srow = lane >> 2;
    const int scol = (lane & 3) * 8;

    // A-merge staging indices: row r = tid>>2 (0..63), chunk kb = tid&3
    const int ar = tid >> 2;
    const int akb = (tid & 3) * 8;
    const int am = m0 + ar;
    const int ab = am >> 11;          // batch
    const int at = am & 2047;         // token

    float4v acc[2][4];
    #pragma unroll
    for (int i=0;i<2;i++)
        #pragma unroll
        for (int j=0;j<4;j++) acc[i][j] = (float4v){0.f,0.f,0.f,0.f};

    for (int k0 = 0; k0 < TOKDIM; k0 += 32) {
        __syncthreads();
        {
            // merge-stage A: 8 consecutive k share one head h
            const int k = k0 + akb;
            const int h = k >> 6;
            const int bh = ab*HEADS + h;
            const float l = PL[bh*SEQ + at] + PL[BH*SEQ + bh*SEQ + at];
            const float inv = 1.0f / l;
            const float* p0 = &PO[(size_t)am*TOKDIM + k];
            const float* p1 = p0 + (size_t)MROWS*TOKDIM;
            float4v a0 = *(const float4v*)p0 + *(const float4v*)p1;
            float4v a1 = *(const float4v*)(p0+4) + *(const float4v*)(p1+4);
            union { int i[4]; short8 s8; } pk;
            pk.i[0] = packrn(a0[0]*inv, a0[1]*inv);
            pk.i[1] = packrn(a0[2]*inv, a0[3]*inv);
            pk.i[2] = packrn(a1[0]*inv, a1[1]*inv);
            pk.i[3] = packrn(a1[2]*inv, a1[3]*inv);
            *(short8*)&As[ar*32 + akb] = pk.s8;
        }
        #pragma unroll
        for (int j=0;j<2;++j) {
            const int rb = (wave*2 + j) * 16;
            stage16(&W[(size_t)(n0 + rb + srow)*TOKDIM + k0 + scol], &Bs[rb*32]);
        }
        __syncthreads();

        short8 af[2], bfr[4];
        #pragma unroll
        for (int i=0;i<2;i++) af[i]  = *(const short8*)&As[(wm*32 + i*16 + col16)*32 + quad*8];
        #pragma unroll
        for (int j=0;j<4;j++) bfr[j] = *(const short8*)&Bs[(wn*64 + j*16 + col16)*32 + quad*8];
        #pragma unroll
        for (int i=0;i<2;i++)
            #pragma unroll
            for (int j=0;j<4;j++)
                acc[i][j] = __builtin_amdgcn_mfma_f32_16x16x32_bf16(af[i], bfr[j], acc[i][j], 0,0,0);
    }

    #pragma unroll
    for (int i=0;i<2;i++)
        #pragma unroll
        for (int j=0;j<4;j++) {
            const int n = n0 + wn*64 + j*16 + col16;
            const float bn = bias[n];
            #pragma unroll
            for (int r=0;r<4;r++) {
                const int m = m0 + wm*32 + i*16 + quad*4 + r;
                C[(size_t)m*TOKDIM + n] = acc[i][j][r] + bn;
            }
        }
}

// ---------------------------------------------------------------------------
// Flash attention v5: global split-K x2 -> grid (16, 32, 2) = 1024 blocks
// (4 blocks/CU). Block = 128 q, 4 waves: wave (qh=w&1, kh2=w>>1) owns 64 q
// and 512 keys (8 x 64-key tiles) at kbase = kspl*1024 + kh2*512.
// In-register P via key permutation (16x16x32 only), exp2-domain no-max
// softmax. In-block kh2 merge via LDS; block writes UNNORMALIZED fp32
// partial O and partial lsum (normalization fused into gemm_out staging).
// ---------------------------------------------------------------------------
#define AQB 128
#define KT  64
#define VLD 72
#define NTH 8      // tiles per wave (512 keys)

__global__ __launch_bounds__(256, 4)
void attn_kernel(const short* __restrict__ Q, const short* __restrict__ K,
                 const short* __restrict__ Vt, float* __restrict__ PO,
                 float* __restrict__ PL)
{
    __shared__ __align__(16) short SL[2*2*KT*VLD];   // 36864 B

    const int tid   = threadIdx.x;
    const int lane  = tid & 63;
    const int wave  = tid >> 6;
    const int col16 = lane & 15, quad = lane >> 4;
    const int bh   = blockIdx.y;
    const int kspl = blockIdx.z;
    const int qh  = wave & 1;
    const int kh2 = wave >> 1;
    const int qb  = blockIdx.x*AQB + qh*64;

    const short* Qb = Q  + (size_t)bh*SEQ*HDIM;
    const short* Kb = K  + (size_t)bh*SEQ*HDIM;
    const short* Vb = Vt + (size_t)bh*HDIM*SEQ;

    short* Kcs = &SL[kh2*2*KT*VLD];
    short* Vcs = Kcs + KT*VLD;

    const int local = tid & 127;
    const int sr = local >> 1;
    const int sc = (local & 1) * 32;
    const int rho = sr & 31;
    const int kslot = (sr & 32) + ((rho & 4) << 2) + ((rho & 24) >> 1) + (rho & 3);
    const int kbase = kspl*1024 + kh2*512;

    const float qscale = 0.125f * 1.44269504088896f;
    short8 qf[4][2];
    #pragma unroll
    for (int qg=0; qg<4; ++qg)
        #pragma unroll
        for (int kk=0; kk<2; ++kk) {
            short8 raw = *(const short8*)&Qb[(size_t)(qb+qg*16+col16)*HDIM + kk*32 + quad*8];
            #pragma unroll
            for (int j=0;j<8;++j) raw[j] = f2b(b2f(raw[j]) * qscale);
            qf[qg][kk] = raw;
        }

    float4v o[4][4];
    #pragma unroll
    for (int qg=0;qg<4;qg++)
        #pragma unroll
        for (int dt=0;dt<4;dt++) o[qg][dt] = (float4v){0.f,0.f,0.f,0.f};
    float lsum[4] = {0.f,0.f,0.f,0.f};

    // stage tile 0 of this stream
    {
        #pragma unroll
        for (int i=0;i<4;++i) {
            *(short8*)&Kcs[kslot*VLD + sc + i*8] =
                *(const short8*)&Kb[(size_t)(kbase + sr)*HDIM + sc + i*8];
            *(short8*)&Vcs[sr*VLD + sc + i*8] =
                *(const short8*)&Vb[(size_t)sr*SEQ + kbase + sc + i*8];
        }
    }
    __syncthreads();

    for (int t = 0; t < NTH; ++t) {
        short8 nk[4], nv[4];
        const bool more = (t + 1 < NTH);
        if (more) {
            const int g1 = kbase + (t+1)*KT;
            #pragma unroll
            for (int i=0;i<4;++i) {
                nk[i] = *(const short8*)&Kb[(size_t)(g1 + sr)*HDIM + sc + i*8];
                nv[i] = *(const short8*)&Vb[(size_t)sr*SEQ + g1 + sc + i*8];
            }
        }

        #pragma unroll
        for (int kk = 0; kk < 2; ++kk) {
            short8 ka[2][2];
            #pragma unroll
            for (int nt=0; nt<2; ++nt)
                #pragma unroll
                for (int kh=0; kh<2; ++kh)
                    ka[nt][kh] = *(const short8*)&Kcs[(kk*32 + nt*16 + col16)*VLD + kh*32 + quad*8];
            short8 va[4];
            #pragma unroll
            for (int dt=0; dt<4; ++dt)
                va[dt] = *(const short8*)&Vcs[(dt*16 + col16)*VLD + kk*32 + quad*8];

            #pragma unroll
            for (int qg=0; qg<4; ++qg) {
                float4v st[2];
                #pragma unroll
                for (int nt=0; nt<2; ++nt) {
                    float4v z = (float4v){0.f,0.f,0.f,0.f};
                    z = __builtin_amdgcn_mfma_f32_16x16x32_bf16(ka[nt][0], qf[qg][0], z, 0,0,0);
                    z = __builtin_amdgcn_mfma_f32_16x16x32_bf16(ka[nt][1], qf[qg][1], z, 0,0,0);
                    st[nt] = z;
                }
                union { int i[4]; short8 s8; } pb;
                float p00 = hexp2(st[0][0]), p01 = hexp2(st[0][1]);
                float p02 = hexp2(st[0][2]), p03 = hexp2(st[0][3]);
                float p10 = hexp2(st[1][0]), p11 = hexp2(st[1][1]);
                float p12 = hexp2(st[1][2]), p13 = hexp2(st[1][3]);
                lsum[qg] += ((p00+p01) + (p02+p03)) + ((p10+p11) + (p12+p13));
                pb.i[0] = packrn(p00, p01); pb.i[1] = packrn(p02, p03);
                pb.i[2] = packrn(p10, p11); pb.i[3] = packrn(p12, p13);

                #pragma unroll
                for (int dt=0; dt<4; ++dt)
                    o[qg][dt] = __builtin_amdgcn_mfma_f32_16x16x32_bf16(va[dt], pb.s8, o[qg][dt], 0,0,0);
            }
        }

        __syncthreads();
        if (more) {
            #pragma unroll
            for (int i=0;i<4;++i) {
                *(short8*)&Kcs[kslot*VLD + sc + i*8] = nk[i];
                *(short8*)&Vcs[sr*VLD + sc + i*8]    = nv[i];
            }
            __syncthreads();
        }
    }

    #pragma unroll
    for (int qg=0; qg<4; ++qg) {
        lsum[qg] += __shfl_xor(lsum[qg], 16);
        lsum[qg] += __shfl_xor(lsum[qg], 32);
    }

    // merge kh2 halves through LDS
    float* M = (float*)SL;
    float* Mw = M + (qh*64 + lane)*68;
    if (kh2 == 1) {
        #pragma unroll
        for (int qg=0; qg<4; ++qg) {
            #pragma unroll
            for (int dt=0; dt<4; ++dt)
                *(float4v*)&Mw[(qg*4+dt)*4] = o[qg][dt];
            Mw[64+qg] = lsum[qg];
        }
    }
    __syncthreads();
    if (kh2 == 0) {
        const int b = bh >> 4, h = bh & 15;
        float* POk = PO + (size_t)kspl*MROWS*TOKDIM;
        #pragma unroll
        for (int qg=0; qg<4; ++qg) {
            const float ltot = lsum[qg] + Mw[64+qg];
            const int tq = qb + qg*16 + col16;
            if (quad == 0)
                PL[kspl*BH*SEQ + bh*SEQ + tq] = ltot;
            #pragma unroll
            for (int dt=0; dt<4; ++dt) {
                float4v ov = o[qg][dt] + *(const float4v*)&Mw[(qg*4+dt)*4];
                *(float4v*)&POk[((size_t)(b*SEQ + tq))*TOKDIM + h*64 + dt*16 + quad*4] = ov;
            }
        }
    }
}

// ---------------------------------------------------------------------------
extern "C" void kernel_launch(void* const* d_in, const int* in_sizes, int n_in,
                              void* d_out, int out_size, void* d_ws, size_t ws_size,
                              hipStream_t stream)
{
    const float* x    = (const float*)d_in[0];   // [2,2048,1024] fp32
    const float* wqkv = (const float*)d_in[1];   // [3072,1024]   fp32
    const float* wout = (const float*)d_in[2];   // [1024,1024]   fp32
    const float* bout = (const float*)d_in[3];   // [1024]        fp32
    float* out = (float*)d_out;                  // [2,2048,1024] fp32

    char* ws = (char*)d_ws;
    const size_t SZ   = (size_t)BH*SEQ*HDIM*sizeof(short);     // 8 MiB
    const size_t WQB  = (size_t)3*TOKDIM*TOKDIM*sizeof(short); // 6 MiB
    const size_t WOB  = (size_t)TOKDIM*TOKDIM*sizeof(short);   // 2 MiB
    const size_t POB  = (size_t)MROWS*TOKDIM*sizeof(float);    // 16 MiB per split

    short* Xb  = (short*)ws;
    short* Wqb = (short*)(ws + SZ);
    short* Wob = (short*)(ws + SZ + WQB);
    short* Qt  = (short*)(ws + SZ + WQB + WOB);
    short* Kt  = Qt + SZ/2;
    short* Vt  = Kt + SZ/2;
    float* PO  = (float*)(ws + SZ + WQB + WOB + 3*SZ);         // 2 x 16 MiB
    float* PL  = (float*)((char*)PO + 2*POB);                  // 2 x 256 KiB

    const int n8x = (BATCH*SEQ*TOKDIM)/8;
    const int n8q = (3*TOKDIM*TOKDIM)/8;
    const int n8o = (TOKDIM*TOKDIM)/8;
    const int cvt_blocks = (n8x + n8q + n8o + 255) / 256;
    cvt_bf16<<<cvt_blocks, 256, 0, stream>>>(x, Xb, n8x, wqkv, Wqb, n8q, wout, Wob, n8o);

    gemm_qkv<<<dim3(MROWS/128, (3*TOKDIM)/128), 256, 0, stream>>>(Xb, Wqb, Qt, Kt, Vt);

    attn_kernel<<<dim3(SEQ/AQB, BH, 2), 256, 0, stream>>>(Qt, Kt, Vt, PO, PL);

    gemm_out<<<dim3(MROWS/64, TOKDIM/128), 256, 0, stream>>>(PO, PL, Wob, bout, out);
}

// Round 12
// 194.474 us; speedup vs baseline: 2.4751x; 2.4751x over previous
//
#include <hip/hip_runtime.h>
#include <hip/hip_bf16.h>

typedef short short4v __attribute__((ext_vector_type(4)));
typedef short short8 __attribute__((ext_vector_type(8)));
typedef float float4v __attribute__((ext_vector_type(4)));

#define HEADS 16
#define HDIM 64
#define TOKDIM 1024
#define SEQ 2048
#define BATCH 2
#define BH (BATCH*HEADS)
#define MROWS (BATCH*SEQ)

__device__ __forceinline__ short f2b(float f) {
    __hip_bfloat16 h = __float2bfloat16(f);
    return *reinterpret_cast<short*>(&h);
}
__device__ __forceinline__ float b2f(short s) {
    __hip_bfloat16 h;
    *reinterpret_cast<short*>(&h) = s;
    return __bfloat162float(h);
}
__device__ __forceinline__ short8 load8_f32_bf16(const float* __restrict__ p) {
    float4v a = *(const float4v*)p;
    float4v b = *(const float4v*)(p + 4);
    short8 r;
    r[0]=f2b(a[0]); r[1]=f2b(a[1]); r[2]=f2b(a[2]); r[3]=f2b(a[3]);
    r[4]=f2b(b[0]); r[5]=f2b(b[1]); r[6]=f2b(b[2]); r[7]=f2b(b[3]);
    return r;
}
// fast pack: RN each fp32 to bf16 (bits+0x8000), byte-pack highs via v_perm
__device__ __forceinline__ int packrn(float a, float b) {
    unsigned ua = __float_as_uint(a) + 0x8000u;
    unsigned ub = __float_as_uint(b) + 0x8000u;
    return (int)__builtin_amdgcn_perm(ub, ua, 0x07060302u);
}
// hardware exp2 (avoid glibc __exp2f macro collision)
__device__ __forceinline__ float hexp2(float x) {
    return __builtin_amdgcn_exp2f(x);
}

// async global->LDS DMA, 16B/lane; LDS dest = wave-uniform base + lane*16
__device__ __forceinline__ void stage16(const void* g, void* l) {
    __builtin_amdgcn_global_load_lds((const __attribute__((address_space(1))) void*)g,
                                     (__attribute__((address_space(3))) void*)l, 16, 0, 0);
}

// ---------------------------------------------------------------------------
// One-time fp32 -> bf16 conversion for x, wqkv, wout.
// ---------------------------------------------------------------------------
__global__ __launch_bounds__(256)
void cvt_bf16(const float* __restrict__ x,  short* __restrict__ xb,  int n8x,
              const float* __restrict__ wq, short* __restrict__ wqb, int n8q,
              const float* __restrict__ wo, short* __restrict__ wob, int n8o)
{
    int i = blockIdx.x*256 + threadIdx.x;
    const float* s; short* d; int off;
    if (i < n8x)                  { s = x;  d = xb;  off = i; }
    else if (i < n8x + n8q)       { s = wq; d = wqb; off = i - n8x; }
    else if (i < n8x + n8q + n8o) { s = wo; d = wob; off = i - n8x - n8q; }
    else return;
    *(short8*)&d[(size_t)off*8] = load8_f32_bf16(&s[(size_t)off*8]);
}

// ---------------------------------------------------------------------------
// QKV GEMM, m97-style staging (unchanged).
// ---------------------------------------------------------------------------
__global__ __launch_bounds__(256)
void gemm_qkv(const short* __restrict__ A, const short* __restrict__ Wq,
              short* __restrict__ Qo, short* __restrict__ Ko, short* __restrict__ Vto)
{
    __shared__ __align__(16) short As[128*32];
    __shared__ __align__(16) short Bs[128*32];
    const int tid  = threadIdx.x;
    const int lane = tid & 63;
    const int wave = tid >> 6;
    const int wm = wave >> 1, wn = wave & 1;
    const int m0 = blockIdx.x * 128;
    const int n0 = blockIdx.y * 128;
    const int col16 = lane & 15, quad = lane >> 4;

    const int srow = lane >> 2;
    const int scol = (lane & 3) * 8;

    float4v acc[4][4];
    #pragma unroll
    for (int i=0;i<4;i++)
        #pragma unroll
        for (int j=0;j<4;j++) acc[i][j] = (float4v){0.f,0.f,0.f,0.f};

    for (int k0 = 0; k0 < TOKDIM; k0 += 32) {
        __syncthreads();
        #pragma unroll
        for (int j=0;j<2;++j) {
            const int rb = (wave*2 + j) * 16;
            stage16(&A[(size_t)(m0 + rb + srow)*TOKDIM + k0 + scol], &As[rb*32]);
        }
        #pragma unroll
        for (int j=0;j<2;++j) {
            const int rb = (wave*2 + j) * 16;
            stage16(&Wq[(size_t)(n0 + rb + srow)*TOKDIM + k0 + scol], &Bs[rb*32]);
        }
        __syncthreads();

        short8 af[4], bfr[4];
        #pragma unroll
        for (int i=0;i<4;i++) af[i]  = *(const short8*)&As[(wm*64 + i*16 + col16)*32 + quad*8];
        #pragma unroll
        for (int j=0;j<4;j++) bfr[j] = *(const short8*)&Bs[(wn*64 + j*16 + col16)*32 + quad*8];
        #pragma unroll
        for (int i=0;i<4;i++)
            #pragma unroll
            for (int j=0;j<4;j++)
                acc[i][j] = __builtin_amdgcn_mfma_f32_16x16x32_bf16(af[i], bfr[j], acc[i][j], 0,0,0);
    }

    #pragma unroll
    for (int i=0;i<4;i++)
        #pragma unroll
        for (int j=0;j<4;j++) {
            const int n = n0 + wn*64 + j*16 + col16;
            const int part = n >> 10;         // 0=Q 1=K 2=V
            const int h = (n & 1023) >> 6;
            const int d = n & 63;
            const int mb = m0 + wm*64 + i*16 + quad*4;
            const int b = mb >> 11;
            const int t = mb & 2047;
            if (part == 2) {
                union { short4v s; int2 i2; } w;
                #pragma unroll
                for (int r=0;r<4;r++) w.s[r] = f2b(acc[i][j][r]);
                *(int2*)&Vto[((size_t)(b*HEADS + h)*HDIM + d)*SEQ + t] = w.i2;
            } else {
                short* dst = (part == 0) ? Qo : Ko;
                #pragma unroll
                for (int r=0;r<4;r++)
                    dst[((size_t)(b*HEADS + h)*SEQ + t + r)*HDIM + d] = f2b(acc[i][j][r]);
            }
        }
}

// ---------------------------------------------------------------------------
// Out GEMM with fused split-K attention merge in the A-staging:
// A[m][k] = (PO0[m][k] + PO1[m][k]) / (PL0[bh][t] + PL1[bh][t]) -> bf16.
// W (bf16) stays DMA-staged. fp32 output + bias.
// ---------------------------------------------------------------------------
__global__ __launch_bounds__(256)
void gemm_out(const float* __restrict__ PO, const float* __restrict__ PL,
              const short* __restrict__ W,
              const float* __restrict__ bias, float* __restrict__ C)
{
    __shared__ __align__(16) short As[64*32];
    __shared__ __align__(16) short Bs[128*32];
    const int tid  = threadIdx.x;
    const int lane = tid & 63;
    const int wave = tid >> 6;
    const int wm = wave >> 1, wn = wave & 1;
    const int m0 = blockIdx.x * 64;
    const int n0 = blockIdx.y * 128;
    const int col16 = lane & 15, quad = lane >> 4;

    const int srow = lane >> 2;
    const int scol = (lane & 3) * 8;

    const int ar = tid >> 2;
    const int akb = (tid & 3) * 8;
    const int am = m0 + ar;
    const int ab = am >> 11;          // batch
    const int at = am & 2047;         // token

    float4v acc[2][4];
    #pragma unroll
    for (int i=0;i<2;i++)
        #pragma unroll
        for (int j=0;j<4;j++) acc[i][j] = (float4v){0.f,0.f,0.f,0.f};

    for (int k0 = 0; k0 < TOKDIM; k0 += 32) {
        __syncthreads();
        {
            const int k = k0 + akb;
            const int h = k >> 6;
            const int bh = ab*HEADS + h;
            const float l = PL[bh*SEQ + at] + PL[BH*SEQ + bh*SEQ + at];
            const float inv = 1.0f / l;
            const float* p0 = &PO[(size_t)am*TOKDIM + k];
            const float* p1 = p0 + (size_t)MROWS*TOKDIM;
            float4v a0 = *(const float4v*)p0 + *(const float4v*)p1;
            float4v a1 = *(const float4v*)(p0+4) + *(const float4v*)(p1+4);
            union { int i[4]; short8 s8; } pk;
            pk.i[0] = packrn(a0[0]*inv, a0[1]*inv);
            pk.i[1] = packrn(a0[2]*inv, a0[3]*inv);
            pk.i[2] = packrn(a1[0]*inv, a1[1]*inv);
            pk.i[3] = packrn(a1[2]*inv, a1[3]*inv);
            *(short8*)&As[ar*32 + akb] = pk.s8;
        }
        #pragma unroll
        for (int j=0;j<2;++j) {
            const int rb = (wave*2 + j) * 16;
            stage16(&W[(size_t)(n0 + rb + srow)*TOKDIM + k0 + scol], &Bs[rb*32]);
        }
        __syncthreads();

        short8 af[2], bfr[4];
        #pragma unroll
        for (int i=0;i<2;i++) af[i]  = *(const short8*)&As[(wm*32 + i*16 + col16)*32 + quad*8];
        #pragma unroll
        for (int j=0;j<4;j++) bfr[j] = *(const short8*)&Bs[(wn*64 + j*16 + col16)*32 + quad*8];
        #pragma unroll
        for (int i=0;i<2;i++)
            #pragma unroll
            for (int j=0;j<4;j++)
                acc[i][j] = __builtin_amdgcn_mfma_f32_16x16x32_bf16(af[i], bfr[j], acc[i][j], 0,0,0);
    }

    #pragma unroll
    for (int i=0;i<2;i++)
        #pragma unroll
        for (int j=0;j<4;j++) {
            const int n = n0 + wn*64 + j*16 + col16;
            const float bn = bias[n];
            #pragma unroll
            for (int r=0;r<4;r++) {
                const int m = m0 + wm*32 + i*16 + quad*4 + r;
                C[(size_t)m*TOKDIM + n] = acc[i][j][r] + bn;
            }
        }
}

// ---------------------------------------------------------------------------
// Flash attention v5b: global split-K x2, grid (16, 32, 2) = 1024 blocks
// (4 blocks/CU by HW limits: VGPR ~112 -> 4 waves/SIMD, LDS 36.8KB -> 4/CU).
// __launch_bounds__(256,2): round-11's (256,4) forced VGPR=64 -> scratch
// spill -> 1.6 GB HBM traffic. (256,2) restores the no-spill allocation;
// hardware occupancy comes from actual VGPR/LDS, not the bound.
// ---------------------------------------------------------------------------
#define AQB 128
#define KT  64
#define VLD 72
#define NTH 8      // tiles per wave (512 keys)

__global__ __launch_bounds__(256, 2)
void attn_kernel(const short* __restrict__ Q, const short* __restrict__ K,
                 const short* __restrict__ Vt, float* __restrict__ PO,
                 float* __restrict__ PL)
{
    __shared__ __align__(16) short SL[2*2*KT*VLD];   // 36864 B

    const int tid   = threadIdx.x;
    const int lane  = tid & 63;
    const int wave  = tid >> 6;
    const int col16 = lane & 15, quad = lane >> 4;
    const int bh   = blockIdx.y;
    const int kspl = blockIdx.z;
    const int qh  = wave & 1;
    const int kh2 = wave >> 1;
    const int qb  = blockIdx.x*AQB + qh*64;

    const short* Qb = Q  + (size_t)bh*SEQ*HDIM;
    const short* Kb = K  + (size_t)bh*SEQ*HDIM;
    const short* Vb = Vt + (size_t)bh*HDIM*SEQ;

    short* Kcs = &SL[kh2*2*KT*VLD];
    short* Vcs = Kcs + KT*VLD;

    const int local = tid & 127;
    const int sr = local >> 1;
    const int sc = (local & 1) * 32;
    const int rho = sr & 31;
    const int kslot = (sr & 32) + ((rho & 4) << 2) + ((rho & 24) >> 1) + (rho & 3);
    const int kbase = kspl*1024 + kh2*512;

    const float qscale = 0.125f * 1.44269504088896f;
    short8 qf[4][2];
    #pragma unroll
    for (int qg=0; qg<4; ++qg)
        #pragma unroll
        for (int kk=0; kk<2; ++kk) {
            short8 raw = *(const short8*)&Qb[(size_t)(qb+qg*16+col16)*HDIM + kk*32 + quad*8];
            #pragma unroll
            for (int j=0;j<8;++j) raw[j] = f2b(b2f(raw[j]) * qscale);
            qf[qg][kk] = raw;
        }

    float4v o[4][4];
    #pragma unroll
    for (int qg=0;qg<4;qg++)
        #pragma unroll
        for (int dt=0;dt<4;dt++) o[qg][dt] = (float4v){0.f,0.f,0.f,0.f};
    float lsum[4] = {0.f,0.f,0.f,0.f};

    // stage tile 0 of this stream
    {
        #pragma unroll
        for (int i=0;i<4;++i) {
            *(short8*)&Kcs[kslot*VLD + sc + i*8] =
                *(const short8*)&Kb[(size_t)(kbase + sr)*HDIM + sc + i*8];
            *(short8*)&Vcs[sr*VLD + sc + i*8] =
                *(const short8*)&Vb[(size_t)sr*SEQ + kbase + sc + i*8];
        }
    }
    __syncthreads();

    for (int t = 0; t < NTH; ++t) {
        short8 nk[4], nv[4];
        const bool more = (t + 1 < NTH);
        if (more) {
            const int g1 = kbase + (t+1)*KT;
            #pragma unroll
            for (int i=0;i<4;++i) {
                nk[i] = *(const short8*)&Kb[(size_t)(g1 + sr)*HDIM + sc + i*8];
                nv[i] = *(const short8*)&Vb[(size_t)sr*SEQ + g1 + sc + i*8];
            }
        }

        #pragma unroll
        for (int kk = 0; kk < 2; ++kk) {
            short8 ka[2][2];
            #pragma unroll
            for (int nt=0; nt<2; ++nt)
                #pragma unroll
                for (int kh=0; kh<2; ++kh)
                    ka[nt][kh] = *(const short8*)&Kcs[(kk*32 + nt*16 + col16)*VLD + kh*32 + quad*8];
            short8 va[4];
            #pragma unroll
            for (int dt=0; dt<4; ++dt)
                va[dt] = *(const short8*)&Vcs[(dt*16 + col16)*VLD + kk*32 + quad*8];

            #pragma unroll
            for (int qg=0; qg<4; ++qg) {
                float4v st[2];
                #pragma unroll
                for (int nt=0; nt<2; ++nt) {
                    float4v z = (float4v){0.f,0.f,0.f,0.f};
                    z = __builtin_amdgcn_mfma_f32_16x16x32_bf16(ka[nt][0], qf[qg][0], z, 0,0,0);
                    z = __builtin_amdgcn_mfma_f32_16x16x32_bf16(ka[nt][1], qf[qg][1], z, 0,0,0);
                    st[nt] = z;
                }
                union { int i[4]; short8 s8; } pb;
                float p00 = hexp2(st[0][0]), p01 = hexp2(st[0][1]);
                float p02 = hexp2(st[0][2]), p03 = hexp2(st[0][3]);
                float p10 = hexp2(st[1][0]), p11 = hexp2(st[1][1]);
                float p12 = hexp2(st[1][2]), p13 = hexp2(st[1][3]);
                lsum[qg] += ((p00+p01) + (p02+p03)) + ((p10+p11) + (p12+p13));
                pb.i[0] = packrn(p00, p01); pb.i[1] = packrn(p02, p03);
                pb.i[2] = packrn(p10, p11); pb.i[3] = packrn(p12, p13);

                #pragma unroll
                for (int dt=0; dt<4; ++dt)
                    o[qg][dt] = __builtin_amdgcn_mfma_f32_16x16x32_bf16(va[dt], pb.s8, o[qg][dt], 0,0,0);
            }
        }

        __syncthreads();
        if (more) {
            #pragma unroll
            for (int i=0;i<4;++i) {
                *(short8*)&Kcs[kslot*VLD + sc + i*8] = nk[i];
                *(short8*)&Vcs[sr*VLD + sc + i*8]    = nv[i];
            }
            __syncthreads();
        }
    }

    #pragma unroll
    for (int qg=0; qg<4; ++qg) {
        lsum[qg] += __shfl_xor(lsum[qg], 16);
        lsum[qg] += __shfl_xor(lsum[qg], 32);
    }

    // merge kh2 halves through LDS
    float* M = (float*)SL;
    float* Mw = M + (qh*64 + lane)*68;
    if (kh2 == 1) {
        #pragma unroll
        for (int qg=0; qg<4; ++qg) {
            #pragma unroll
            for (int dt=0; dt<4; ++dt)
                *(float4v*)&Mw[(qg*4+dt)*4] = o[qg][dt];
            Mw[64+qg] = lsum[qg];
        }
    }
    __syncthreads();
    if (kh2 == 0) {
        const int b = bh >> 4, h = bh & 15;
        float* POk = PO + (size_t)kspl*MROWS*TOKDIM;
        #pragma unroll
        for (int qg=0; qg<4; ++qg) {
            const float ltot = lsum[qg] + Mw[64+qg];
            const int tq = qb + qg*16 + col16;
            if (quad == 0)
                PL[kspl*BH*SEQ + bh*SEQ + tq] = ltot;
            #pragma unroll
            for (int dt=0; dt<4; ++dt) {
                float4v ov = o[qg][dt] + *(const float4v*)&Mw[(qg*4+dt)*4];
                *(float4v*)&POk[((size_t)(b*SEQ + tq))*TOKDIM + h*64 + dt*16 + quad*4] = ov;
            }
        }
    }
}

// ---------------------------------------------------------------------------
extern "C" void kernel_launch(void* const* d_in, const int* in_sizes, int n_in,
                              void* d_out, int out_size, void* d_ws, size_t ws_size,
                              hipStream_t stream)
{
    const float* x    = (const float*)d_in[0];   // [2,2048,1024] fp32
    const float* wqkv = (const float*)d_in[1];   // [3072,1024]   fp32
    const float* wout = (const float*)d_in[2];   // [1024,1024]   fp32
    const float* bout = (const float*)d_in[3];   // [1024]        fp32
    float* out = (float*)d_out;                  // [2,2048,1024] fp32

    char* ws = (char*)d_ws;
    const size_t SZ   = (size_t)BH*SEQ*HDIM*sizeof(short);     // 8 MiB
    const size_t WQB  = (size_t)3*TOKDIM*TOKDIM*sizeof(short); // 6 MiB
    const size_t WOB  = (size_t)TOKDIM*TOKDIM*sizeof(short);   // 2 MiB
    const size_t POB  = (size_t)MROWS*TOKDIM*sizeof(float);    // 16 MiB per split

    short* Xb  = (short*)ws;
    short* Wqb = (short*)(ws + SZ);
    short* Wob = (short*)(ws + SZ + WQB);
    short* Qt  = (short*)(ws + SZ + WQB + WOB);
    short* Kt  = Qt + SZ/2;
    short* Vt  = Kt + SZ/2;
    float* PO  = (float*)(ws + SZ + WQB + WOB + 3*SZ);         // 2 x 16 MiB
    float* PL  = (float*)((char*)PO + 2*POB);                  // 2 x 256 KiB

    const int n8x = (BATCH*SEQ*TOKDIM)/8;
    const int n8q = (3*TOKDIM*TOKDIM)/8;
    const int n8o = (TOKDIM*TOKDIM)/8;
    const int cvt_blocks = (n8x + n8q + n8o + 255) / 256;
    cvt_bf16<<<cvt_blocks, 256, 0, stream>>>(x, Xb, n8x, wqkv, Wqb, n8q, wout, Wob, n8o);

    gemm_qkv<<<dim3(MROWS/128, (3*TOKDIM)/128), 256, 0, stream>>>(Xb, Wqb, Qt, Kt, Vt);

    attn_kernel<<<dim3(SEQ/AQB, BH, 2), 256, 0, stream>>>(Qt, Kt, Vt, PO, PL);

    gemm_out<<<dim3(MROWS/64, TOKDIM/128), 256, 0, stream>>>(PO, PL, Wob, bout, out);
}